// Round 1
// baseline (1109.499 us; speedup 1.0000x reference)
//
#include <hip/hip_runtime.h>
#include <math.h>

// Problem constants (B=8192 rows, D=256 features)
#define NB 8192
#define ND 256

constexpr int BM = 64, BN = 64, BK = 64;
constexpr int JCHUNK = 1024;           // columns handled per workgroup
constexpr int NJT = JCHUNK / BN;       // 16 j-tiles per workgroup
constexpr int KSTEPS = ND / BK;        // 4

// ---------------------------------------------------------------- init
__global__ void init_kernel(float* minpos, float* maxneg, float* negsum,
                            float* possum, float* negcnt, float* poscnt,
                            float* out) {
    int i = blockIdx.x * 256 + threadIdx.x;
    if (i < NB) {
        minpos[i] = __int_as_float(0x7f800000);   // +inf
        maxneg[i] = __int_as_float(0xff800000);   // -inf
        negsum[i] = 0.f; possum[i] = 0.f;
        negcnt[i] = 0.f; poscnt[i] = 0.f;
    }
    if (blockIdx.x == 0 && threadIdx.x == 0) out[0] = 0.f;
}

// ---------------------------------------------------------- normalize
// One wave per row: f = x / (||x|| + 1e-12); also sq[i] = sum(f*f) from
// the rounded stored values (matches reference order of operations).
__global__ void normalize_kernel(const float* __restrict__ feats,
                                 float* __restrict__ fn,
                                 float* __restrict__ sq) {
    int row = blockIdx.x;
    int lane = threadIdx.x;                     // 64 lanes, 4 floats each
    float4 v = ((const float4*)(feats + (size_t)row * ND))[lane];
    float s = v.x*v.x + v.y*v.y + v.z*v.z + v.w*v.w;
    #pragma unroll
    for (int off = 32; off > 0; off >>= 1) s += __shfl_xor(s, off, 64);
    float inv = 1.0f / (sqrtf(s) + 1e-12f);
    float4 w = make_float4(v.x*inv, v.y*inv, v.z*inv, v.w*inv);
    ((float4*)(fn + (size_t)row * ND))[lane] = w;
    float s2 = w.x*w.x + w.y*w.y + w.z*w.z + w.w*w.w;
    #pragma unroll
    for (int off = 32; off > 0; off >>= 1) s2 += __shfl_xor(s2, off, 64);
    if (lane == 0) sq[row] = s2;
}

// ---------------------------------------------------- fused GEMM passes
// PASS 1: per-row min_pos / max_neg mining.
// PASS 2: masked exp-sums + counts using pass-1 thresholds.
// Tiling: 64x64 tile per WG iteration, 256 threads, 4x4 micro-tile,
// K staged in BK=64 chunks; LDS holds A,B transposed [k][m] so the
// inner loop reads are float4 (ds_read_b128, broadcast / 2-way = free).
template <int PASS>
__global__ __launch_bounds__(256) void pass_kernel(
    const float* __restrict__ fn, const float* __restrict__ sq,
    const int* __restrict__ labels,
    float* __restrict__ minpos, float* __restrict__ maxneg,
    float* __restrict__ negsum, float* __restrict__ possum,
    float* __restrict__ negcnt, float* __restrict__ poscnt)
{
    __shared__ float As[BK * BM];   // [kk][m]  16 KB
    __shared__ float Bs[BK * BN];   // [kk][n]  16 KB

    const int tid = threadIdx.x;
    const int tx = tid & 15;        // micro-tile col group
    const int ty = tid >> 4;        // micro-tile row group (0..15)
    const int i0 = blockIdx.x * BM;
    const int jbase = blockIdx.y * JCHUNK;

    // staging mapping: row m = tid/4, quad q = tid%4 (16 rows x 64B per wave)
    const int sm = tid >> 2;
    const int sq_ = tid & 3;

    // per-thread row-invariant data (4 rows: ty*4+d)
    int   labi[4]; float sqi[4];
    float mp[4], mn[4];
    float minv[4], maxv[4];
    float nsum[4] = {0,0,0,0}, psum[4] = {0,0,0,0};
    float ncnt[4] = {0,0,0,0}, pcnt[4] = {0,0,0,0};
    #pragma unroll
    for (int d = 0; d < 4; ++d) {
        int r = i0 + ty*4 + d;
        labi[d] = labels[r];
        sqi[d]  = sq[r];
        minv[d] = __int_as_float(0x7f800000);
        maxv[d] = __int_as_float(0xff800000);
        if (PASS == 2) { mp[d] = minpos[r]; mn[d] = maxneg[r]; }
    }

    for (int jt = 0; jt < NJT; ++jt) {
        const int j0 = jbase + jt * BN;

        float acc[4][4];
        #pragma unroll
        for (int a = 0; a < 4; ++a)
            #pragma unroll
            for (int b = 0; b < 4; ++b) acc[a][b] = 0.f;

        for (int kc = 0; kc < KSTEPS; ++kc) {
            __syncthreads();   // previous tile's readers done
            const float* srcA = fn + (size_t)(i0 + sm) * ND + kc * BK;
            const float* srcB = fn + (size_t)(j0 + sm) * ND + kc * BK;
            #pragma unroll
            for (int h = 0; h < 4; ++h) {
                int k0 = h * 16 + sq_ * 4;
                float4 va = *(const float4*)(srcA + k0);
                As[(k0+0)*BM + sm] = va.x;
                As[(k0+1)*BM + sm] = va.y;
                As[(k0+2)*BM + sm] = va.z;
                As[(k0+3)*BM + sm] = va.w;
                float4 vb = *(const float4*)(srcB + k0);
                Bs[(k0+0)*BN + sm] = vb.x;
                Bs[(k0+1)*BN + sm] = vb.y;
                Bs[(k0+2)*BN + sm] = vb.z;
                Bs[(k0+3)*BN + sm] = vb.w;
            }
            __syncthreads();
            #pragma unroll
            for (int kk = 0; kk < BK; ++kk) {
                float4 a = *(const float4*)&As[kk*BM + ty*4];
                float4 b = *(const float4*)&Bs[kk*BN + tx*4];
                acc[0][0] = fmaf(a.x, b.x, acc[0][0]);
                acc[0][1] = fmaf(a.x, b.y, acc[0][1]);
                acc[0][2] = fmaf(a.x, b.z, acc[0][2]);
                acc[0][3] = fmaf(a.x, b.w, acc[0][3]);
                acc[1][0] = fmaf(a.y, b.x, acc[1][0]);
                acc[1][1] = fmaf(a.y, b.y, acc[1][1]);
                acc[1][2] = fmaf(a.y, b.z, acc[1][2]);
                acc[1][3] = fmaf(a.y, b.w, acc[1][3]);
                acc[2][0] = fmaf(a.z, b.x, acc[2][0]);
                acc[2][1] = fmaf(a.z, b.y, acc[2][1]);
                acc[2][2] = fmaf(a.z, b.z, acc[2][2]);
                acc[2][3] = fmaf(a.z, b.w, acc[2][3]);
                acc[3][0] = fmaf(a.w, b.x, acc[3][0]);
                acc[3][1] = fmaf(a.w, b.y, acc[3][1]);
                acc[3][2] = fmaf(a.w, b.z, acc[3][2]);
                acc[3][3] = fmaf(a.w, b.w, acc[3][3]);
            }
        }

        // epilogue for this 64x64 tile
        int labj[4]; float sqj[4];
        #pragma unroll
        for (int d = 0; d < 4; ++d) {
            labj[d] = labels[j0 + tx*4 + d];
            sqj[d]  = sq[j0 + tx*4 + d];
        }
        #pragma unroll
        for (int di = 0; di < 4; ++di) {
            #pragma unroll
            for (int dj = 0; dj < 4; ++dj) {
                float dot  = acc[di][dj];
                float d2   = sqi[di] + sqj[dj] - 2.0f * dot;
                float dist = sqrtf(fmaxf(d2, 1e-12f));
                bool same  = (labi[di] == labj[dj]);
                bool posb  = same && (dist < (1.0f - 1e-5f));
                if (PASS == 1) {
                    if (posb)  minv[di] = fminf(minv[di], dist);
                    if (!same) maxv[di] = fmaxf(maxv[di], dist);
                } else {
                    if (!same && (dist + 0.1f > mp[di])) {
                        nsum[di] += expf(-40.0f * (dist - 1.0f));
                        ncnt[di] += 1.0f;
                    }
                    if (posb && (dist - 0.1f < mn[di])) {
                        psum[di] += expf(2.0f * (dist - 0.7f));
                        pcnt[di] += 1.0f;
                    }
                }
            }
        }
    }

    // reduce across the 16 tx lanes (same ty group within a wave)
    #pragma unroll
    for (int d = 0; d < 4; ++d) {
        if (PASS == 1) {
            #pragma unroll
            for (int off = 8; off > 0; off >>= 1) {
                minv[d] = fminf(minv[d], __shfl_xor(minv[d], off, 64));
                maxv[d] = fmaxf(maxv[d], __shfl_xor(maxv[d], off, 64));
            }
            if (tx == 0) {
                int r = i0 + ty*4 + d;
                // all candidates >= 0.0f -> int compare == float compare
                atomicMin((int*)&minpos[r], __float_as_int(minv[d]));
                atomicMax((int*)&maxneg[r], __float_as_int(maxv[d]));
            }
        } else {
            #pragma unroll
            for (int off = 8; off > 0; off >>= 1) {
                nsum[d] += __shfl_xor(nsum[d], off, 64);
                psum[d] += __shfl_xor(psum[d], off, 64);
                ncnt[d] += __shfl_xor(ncnt[d], off, 64);
                pcnt[d] += __shfl_xor(pcnt[d], off, 64);
            }
            if (tx == 0) {
                int r = i0 + ty*4 + d;
                atomicAdd(&negsum[r], nsum[d]);
                atomicAdd(&possum[r], psum[d]);
                atomicAdd(&negcnt[r], ncnt[d]);
                atomicAdd(&poscnt[r], pcnt[d]);
            }
        }
    }
}

// ------------------------------------------------------------- finalize
__global__ void finalize_kernel(const float* __restrict__ negsum,
                                const float* __restrict__ possum,
                                const float* __restrict__ negcnt,
                                const float* __restrict__ poscnt,
                                float* out) {
    int i = blockIdx.x * 256 + threadIdx.x;
    float v = 0.f;
    if (i < NB) {
        bool valid = (negcnt[i] >= 0.5f) && (poscnt[i] >= 0.5f);
        if (valid) {
            float nl = log1pf(negsum[i]) * (1.0f / 40.0f);
            float pl = log1pf(possum[i]) / (poscnt[i] + 1e-5f);
            v = nl + pl;
        }
    }
    #pragma unroll
    for (int off = 32; off > 0; off >>= 1) v += __shfl_xor(v, off, 64);
    __shared__ float red[4];
    if ((threadIdx.x & 63) == 0) red[threadIdx.x >> 6] = v;
    __syncthreads();
    if (threadIdx.x == 0)
        atomicAdd(out, (red[0] + red[1] + red[2] + red[3]) * (1.0f / NB));
}

// ------------------------------------------------------------ launcher
extern "C" void kernel_launch(void* const* d_in, const int* in_sizes, int n_in,
                              void* d_out, int out_size, void* d_ws, size_t ws_size,
                              hipStream_t stream) {
    const float* feats  = (const float*)d_in[0];
    const int*   labels = (const int*)d_in[1];
    float* out = (float*)d_out;

    // workspace layout (floats): fn[NB*ND], sq[NB], minpos[NB], maxneg[NB],
    // negsum[NB], possum[NB], negcnt[NB], poscnt[NB]  (~8.6 MB total)
    float* ws = (float*)d_ws;
    float* fn     = ws;
    float* sqv    = fn + (size_t)NB * ND;
    float* minpos = sqv + NB;
    float* maxneg = minpos + NB;
    float* negsum = maxneg + NB;
    float* possum = negsum + NB;
    float* negcnt = possum + NB;
    float* poscnt = negcnt + NB;

    init_kernel<<<NB / 256, 256, 0, stream>>>(minpos, maxneg, negsum, possum,
                                              negcnt, poscnt, out);
    normalize_kernel<<<NB, 64, 0, stream>>>(feats, fn, sqv);

    dim3 grid(NB / BM, NB / JCHUNK);   // 128 x 8 = 1024 workgroups
    pass_kernel<1><<<grid, 256, 0, stream>>>(fn, sqv, labels, minpos, maxneg,
                                             negsum, possum, negcnt, poscnt);
    pass_kernel<2><<<grid, 256, 0, stream>>>(fn, sqv, labels, minpos, maxneg,
                                             negsum, possum, negcnt, poscnt);
    finalize_kernel<<<NB / 256, 256, 0, stream>>>(negsum, possum, negcnt,
                                                  poscnt, out);
}

// Round 2
// 371.902 us; speedup vs baseline: 2.9833x; 2.9833x over previous
//
#include <hip/hip_runtime.h>
#include <math.h>

// Problem constants (B=8192 rows, D=256 features)
#define NB 8192
#define ND 256

using bf16x8 = __attribute__((ext_vector_type(8))) short;  // 8 bf16 in 4 VGPRs
using f32x4  = __attribute__((ext_vector_type(4))) float;  // MFMA C/D frag

__device__ __forceinline__ unsigned short f2bf(float x) {  // RNE fp32->bf16
    unsigned u = __float_as_uint(x);
    return (unsigned short)((u + 0x7fffu + ((u >> 16) & 1u)) >> 16);
}
__device__ __forceinline__ float bf2f(unsigned short b) {
    return __uint_as_float(((unsigned)b) << 16);
}

// ---------------------------------------------------------------- init
__global__ void init_kernel(float* minpos, float* maxneg, float* negsum,
                            float* possum, float* negcnt, float* poscnt,
                            float* out) {
    int i = blockIdx.x * 256 + threadIdx.x;
    if (i < NB) {
        minpos[i] = __int_as_float(0x7f800000);   // +inf
        maxneg[i] = __int_as_float(0xff800000);   // -inf
        negsum[i] = 0.f; possum[i] = 0.f;
        negcnt[i] = 0.f; poscnt[i] = 0.f;
    }
    if (blockIdx.x == 0 && threadIdx.x == 0) out[0] = 0.f;
}

// ---------------------------------------------------------- normalize
// One wave per row: f = x/(||x||+1e-12), rounded to bf16 (RNE).
// sq[i] = sum of bf16(f)^2 in fp32 — consistent with the MFMA diagonal
// (bf16*bf16 is exact in fp32), so dist(i,i) stays ~1e-4.
__global__ void normalize_kernel(const float* __restrict__ feats,
                                 unsigned short* __restrict__ fnb,
                                 float* __restrict__ sq) {
    int row = blockIdx.x * 4 + (threadIdx.x >> 6);
    int lane = threadIdx.x & 63;
    float4 v = ((const float4*)(feats + (size_t)row * ND))[lane];
    float s = v.x*v.x + v.y*v.y + v.z*v.z + v.w*v.w;
    #pragma unroll
    for (int off = 32; off > 0; off >>= 1) s += __shfl_xor(s, off, 64);
    float inv = 1.0f / (sqrtf(s) + 1e-12f);
    ushort4 w;
    w.x = f2bf(v.x * inv); w.y = f2bf(v.y * inv);
    w.z = f2bf(v.z * inv); w.w = f2bf(v.w * inv);
    ((ushort4*)(fnb + (size_t)row * ND))[lane] = w;
    float ax = bf2f(w.x), ay = bf2f(w.y), az = bf2f(w.z), aw = bf2f(w.w);
    float s2 = ax*ax + ay*ay + az*az + aw*aw;
    #pragma unroll
    for (int off = 32; off > 0; off >>= 1) s2 += __shfl_xor(s2, off, 64);
    if (lane == 0) sq[row] = s2;
}

// ---------------------------------------------------- fused MFMA passes
// dist[i][j] from dot = fn_i . fn_j via mfma_f32_16x16x32_bf16.
// 128x128 tile / WG, 4 waves in 2x2, each wave 64x64 via 4x4 frags.
// LDS: packed 128B rows, XOR-swizzled 16B chunks (slot = c ^ (row&7)) so
// staging writes AND frag reads are 2-lanes/bank (free).
// PASS 1 mines per-row min_pos / max_neg; PASS 2 does the masked exp sums.
template <int PASS>
__global__ __launch_bounds__(256) void pass_kernel(
    const unsigned short* __restrict__ fnb, const float* __restrict__ sq,
    const int* __restrict__ labels,
    float* __restrict__ minpos, float* __restrict__ maxneg,
    float* __restrict__ negsum, float* __restrict__ possum,
    float* __restrict__ negcnt, float* __restrict__ poscnt)
{
    __shared__ __align__(16) unsigned short As[128 * 64];  // 16 KB
    __shared__ __align__(16) unsigned short Bs[128 * 64];  // 16 KB

    const int tid  = threadIdx.x;
    const int lane = tid & 63;
    const int wid  = tid >> 6;
    const int wm   = wid >> 1;       // wave row (0..1)
    const int wn   = wid & 1;        // wave col (0..1)
    const int i0   = blockIdx.x * 128;
    const int j0   = blockIdx.y * 128;

    f32x4 acc[4][4];
    #pragma unroll
    for (int mt = 0; mt < 4; ++mt)
        #pragma unroll
        for (int nt = 0; nt < 4; ++nt)
            acc[mt][nt] = (f32x4){0.f, 0.f, 0.f, 0.f};

    const int q   = lane >> 4;       // quad within wave (0..3)
    const int c16 = lane & 15;

    for (int kc = 0; kc < ND / 64; ++kc) {
        __syncthreads();             // previous iteration's readers done
        // stage 128 rows x 64 bf16 (8 chunks of 16B per row) for A and B
        #pragma unroll
        for (int h = 0; h < 4; ++h) {
            int cid = h * 256 + tid;         // 0..1023
            int r = cid >> 3, c = cid & 7;
            int sc = c ^ (r & 7);            // swizzled slot
            float4 va = *(const float4*)(fnb + (size_t)(i0 + r) * ND + kc * 64 + c * 8);
            *(float4*)(As + r * 64 + sc * 8) = va;
            float4 vb = *(const float4*)(fnb + (size_t)(j0 + r) * ND + kc * 64 + c * 8);
            *(float4*)(Bs + r * 64 + sc * 8) = vb;
        }
        __syncthreads();
        #pragma unroll
        for (int ks = 0; ks < 2; ++ks) {     // two K=32 sub-steps
            bf16x8 af[4], bfr[4];
            #pragma unroll
            for (int mt = 0; mt < 4; ++mt) {
                int r = wm * 64 + mt * 16 + c16;
                int c = ks * 4 + q;
                af[mt] = *(const bf16x8*)(As + r * 64 + (c ^ (r & 7)) * 8);
            }
            #pragma unroll
            for (int nt = 0; nt < 4; ++nt) {
                int r = wn * 64 + nt * 16 + c16;
                int c = ks * 4 + q;
                bfr[nt] = *(const bf16x8*)(Bs + r * 64 + (c ^ (r & 7)) * 8);
            }
            #pragma unroll
            for (int mt = 0; mt < 4; ++mt)
                #pragma unroll
                for (int nt = 0; nt < 4; ++nt)
                    acc[mt][nt] = __builtin_amdgcn_mfma_f32_16x16x32_bf16(
                        af[mt], bfr[nt], acc[mt][nt], 0, 0, 0);
        }
    }

    // ---- epilogue: C/D layout col=lane&15, row=quad*4+reg (m89/m91) ----
    int labj[4]; float sqj[4];
    #pragma unroll
    for (int nt = 0; nt < 4; ++nt) {
        int j = j0 + wn * 64 + nt * 16 + c16;
        labj[nt] = labels[j];
        sqj[nt]  = sq[j];
    }

    #pragma unroll
    for (int mt = 0; mt < 4; ++mt) {
        int ibase = i0 + wm * 64 + mt * 16 + q * 4;
        #pragma unroll
        for (int reg = 0; reg < 4; ++reg) {
            int i = ibase + reg;
            int   labi = labels[i];
            float sqi  = sq[i];
            if (PASS == 1) {
                float mn = __int_as_float(0x7f800000);
                float mx = __int_as_float(0xff800000);
                #pragma unroll
                for (int nt = 0; nt < 4; ++nt) {
                    float dot  = acc[mt][nt][reg];
                    float d2   = sqi + sqj[nt] - 2.0f * dot;
                    float dist = sqrtf(fmaxf(d2, 1e-12f));
                    bool same  = (labi == labj[nt]);
                    if (same && dist < (1.0f - 1e-5f)) mn = fminf(mn, dist);
                    if (!same)                          mx = fmaxf(mx, dist);
                }
                #pragma unroll
                for (int off = 8; off > 0; off >>= 1) {
                    mn = fminf(mn, __shfl_xor(mn, off, 64));
                    mx = fmaxf(mx, __shfl_xor(mx, off, 64));
                }
                if (c16 == 0) {
                    // candidates >= 0 -> int order == float order
                    atomicMin((int*)&minpos[i], __float_as_int(mn));
                    atomicMax((int*)&maxneg[i], __float_as_int(mx));
                }
            } else {
                float mp  = minpos[i];
                float mxn = maxneg[i];
                float ns = 0.f, ps = 0.f, nc = 0.f, pc = 0.f;
                #pragma unroll
                for (int nt = 0; nt < 4; ++nt) {
                    float dot  = acc[mt][nt][reg];
                    float d2   = sqi + sqj[nt] - 2.0f * dot;
                    float dist = sqrtf(fmaxf(d2, 1e-12f));
                    bool same  = (labi == labj[nt]);
                    if (same) {
                        if (dist < (1.0f - 1e-5f) && dist - 0.1f < mxn) {
                            ps += __expf(2.0f * (dist - 0.7f));
                            pc += 1.0f;
                        }
                    } else if (dist + 0.1f > mp) {
                        ns += __expf(-40.0f * (dist - 1.0f));
                        nc += 1.0f;
                    }
                }
                #pragma unroll
                for (int off = 8; off > 0; off >>= 1) {
                    ns += __shfl_xor(ns, off, 64);
                    ps += __shfl_xor(ps, off, 64);
                    nc += __shfl_xor(nc, off, 64);
                    pc += __shfl_xor(pc, off, 64);
                }
                if (c16 == 0) {
                    atomicAdd(&negsum[i], ns);
                    atomicAdd(&possum[i], ps);
                    atomicAdd(&negcnt[i], nc);
                    atomicAdd(&poscnt[i], pc);
                }
            }
        }
    }
}

// ------------------------------------------------------------- finalize
__global__ void finalize_kernel(const float* __restrict__ negsum,
                                const float* __restrict__ possum,
                                const float* __restrict__ negcnt,
                                const float* __restrict__ poscnt,
                                float* out) {
    int i = blockIdx.x * 256 + threadIdx.x;
    float v = 0.f;
    if (i < NB) {
        bool valid = (negcnt[i] >= 0.5f) && (poscnt[i] >= 0.5f);
        if (valid) {
            float nl = log1pf(negsum[i]) * (1.0f / 40.0f);
            float pl = log1pf(possum[i]) / (poscnt[i] + 1e-5f);
            v = nl + pl;
        }
    }
    #pragma unroll
    for (int off = 32; off > 0; off >>= 1) v += __shfl_xor(v, off, 64);
    __shared__ float red[4];
    if ((threadIdx.x & 63) == 0) red[threadIdx.x >> 6] = v;
    __syncthreads();
    if (threadIdx.x == 0)
        atomicAdd(out, (red[0] + red[1] + red[2] + red[3]) * (1.0f / NB));
}

// ------------------------------------------------------------ launcher
extern "C" void kernel_launch(void* const* d_in, const int* in_sizes, int n_in,
                              void* d_out, int out_size, void* d_ws, size_t ws_size,
                              hipStream_t stream) {
    const float* feats  = (const float*)d_in[0];
    const int*   labels = (const int*)d_in[1];
    float* out = (float*)d_out;

    // workspace: fnb bf16[NB*ND] (4 MB) then fp32 row arrays
    unsigned short* fnb = (unsigned short*)d_ws;
    float* sqv    = (float*)(fnb + (size_t)NB * ND);
    float* minpos = sqv + NB;
    float* maxneg = minpos + NB;
    float* negsum = maxneg + NB;
    float* possum = negsum + NB;
    float* negcnt = possum + NB;
    float* poscnt = negcnt + NB;

    init_kernel<<<NB / 256, 256, 0, stream>>>(minpos, maxneg, negsum, possum,
                                              negcnt, poscnt, out);
    normalize_kernel<<<NB / 4, 256, 0, stream>>>(feats, fnb, sqv);

    dim3 grid(NB / 128, NB / 128);   // 64 x 64 = 4096 workgroups
    pass_kernel<1><<<grid, 256, 0, stream>>>(fnb, sqv, labels, minpos, maxneg,
                                             negsum, possum, negcnt, poscnt);
    pass_kernel<2><<<grid, 256, 0, stream>>>(fnb, sqv, labels, minpos, maxneg,
                                             negsum, possum, negcnt, poscnt);
    finalize_kernel<<<NB / 256, 256, 0, stream>>>(negsum, possum, negcnt,
                                                  poscnt, out);
}

// Round 3
// 235.505 us; speedup vs baseline: 4.7112x; 1.5792x over previous
//
#include <hip/hip_runtime.h>
#include <math.h>

// Problem constants (B=8192 rows, D=256 features)
#define NB 8192
#define ND 256

using bf16x8 = __attribute__((ext_vector_type(8))) short;  // 8 bf16 in 4 VGPRs
using f32x4  = __attribute__((ext_vector_type(4))) float;  // MFMA C/D frag

#define POS2 0.99998000f   // (1 - 1e-5)^2, pos_mask_ threshold in d2 space
#define F_INF  __int_as_float(0x7f800000)
#define F_NINF __int_as_float(0xff800000)

__device__ __forceinline__ unsigned short f2bf(float x) {  // RNE fp32->bf16
    unsigned u = __float_as_uint(x);
    return (unsigned short)((u + 0x7fffu + ((u >> 16) & 1u)) >> 16);
}
__device__ __forceinline__ float bf2f(unsigned short b) {
    return __uint_as_float(((unsigned)b) << 16);
}

// ---------------------------------------------------------------- init
__global__ void init_kernel(float* minpos_d2, float* maxneg_d2, float* negsum,
                            float* possum, float* poscnt, float* out) {
    int i = blockIdx.x * 256 + threadIdx.x;
    if (i < NB) {
        minpos_d2[i] = F_INF;
        maxneg_d2[i] = F_NINF;
        negsum[i] = 0.f; possum[i] = 0.f; poscnt[i] = 0.f;
    }
    if (blockIdx.x == 0 && threadIdx.x == 0) out[0] = 0.f;
}

// ---------------------------------------------------------- normalize
__global__ void normalize_kernel(const float* __restrict__ feats,
                                 unsigned short* __restrict__ fnb,
                                 float* __restrict__ sq) {
    int row = blockIdx.x * 4 + (threadIdx.x >> 6);
    int lane = threadIdx.x & 63;
    float4 v = ((const float4*)(feats + (size_t)row * ND))[lane];
    float s = v.x*v.x + v.y*v.y + v.z*v.z + v.w*v.w;
    #pragma unroll
    for (int off = 32; off > 0; off >>= 1) s += __shfl_xor(s, off, 64);
    float inv = 1.0f / (sqrtf(s) + 1e-12f);
    ushort4 w;
    w.x = f2bf(v.x * inv); w.y = f2bf(v.y * inv);
    w.z = f2bf(v.z * inv); w.w = f2bf(v.w * inv);
    ((ushort4*)(fnb + (size_t)row * ND))[lane] = w;
    float ax = bf2f(w.x), ay = bf2f(w.y), az = bf2f(w.z), aw = bf2f(w.w);
    float s2 = ax*ax + ay*ay + az*az + aw*aw;
    #pragma unroll
    for (int off = 32; off > 0; off >>= 1) s2 += __shfl_xor(s2, off, 64);
    if (lane == 0) sq[row] = s2;
}

// ---------------------------------------------------- fused MFMA passes
// WG tile: 64 i-rows x 1024 j-cols (8 j-tiles of 128). A (64x256 bf16,
// 32 KB) staged in LDS once; B chunk (128x64, 16 KB) staged per kc.
// Waves 2x2: wave-tile 32x64 = 2x4 frags of 16x16. Stats accumulate in
// registers across the whole j-chunk; one reduce+atomic set per WG.
// PASS 1: mine per-row min_pos / max_neg in d2 space (sqrt monotone).
// PASS 2: masked exp sums with thresholds pre-converted to d2 space.
template <int PASS>
__global__ __launch_bounds__(256, 3) void pass_kernel(
    const unsigned short* __restrict__ fnb, const float* __restrict__ sq,
    const int* __restrict__ labels,
    float* __restrict__ minpos_d2, float* __restrict__ maxneg_d2,
    float* __restrict__ negsum, float* __restrict__ possum,
    float* __restrict__ poscnt)
{
    __shared__ __align__(16) unsigned short As[64 * 256];  // 32 KB, full K
    __shared__ __align__(16) unsigned short Bs[128 * 64];  // 16 KB, one kc

    const int tid  = threadIdx.x;
    const int lane = tid & 63;
    const int wid  = tid >> 6;
    const int wm   = wid >> 1;       // wave row (0..1) -> 32 i-rows
    const int wn   = wid & 1;        // wave col (0..1) -> 64 j-cols
    const int q    = lane >> 4;
    const int c16  = lane & 15;
    const int i0   = blockIdx.x * 64;
    const int jbase = blockIdx.y * 1024;

    // ---- per-lane i-row invariants (8 rows: (k>>2)*16 + q*4 + (k&3)) ----
    int   labi[8]; float sqi[8];
    float mnd2[8], mxd2[8];          // pass 1 accumulators
    float tneg[8], tpos[8];          // pass 2 thresholds (d2 space)
    float ns[8], ps[8], pc[8];       // pass 2 accumulators
    #pragma unroll
    for (int k = 0; k < 8; ++k) {
        int i = i0 + wm * 32 + (k >> 2) * 16 + q * 4 + (k & 3);
        labi[k] = labels[i];
        sqi[k]  = sq[i];
        if (PASS == 1) {
            mnd2[k] = F_INF; mxd2[k] = F_NINF;
        } else {
            float mp = sqrtf(fmaxf(minpos_d2[i], 1e-12f));  // +inf ok
            float tn = mp - 0.1f;
            tneg[k] = (tn <= 0.f) ? -3.0f : tn * tn;        // d2 > tneg
            float mx = sqrtf(fmaxf(maxneg_d2[i], 1e-12f));
            float tp = mx + 0.1f;
            tpos[k] = fminf(tp * tp, POS2);                 // d2 < tpos
            ns[k] = 0.f; ps[k] = 0.f; pc[k] = 0.f;
        }
    }

    // ---- stage A once: 64 rows x 32 chunks of 16B, swizzled ----
    #pragma unroll
    for (int h = 0; h < 8; ++h) {
        int cid = h * 256 + tid;          // 0..2047
        int r = cid >> 5, c = cid & 31;
        *(float4*)(As + r * 256 + (c ^ (r & 7)) * 8) =
            *(const float4*)(fnb + (size_t)(i0 + r) * ND + c * 8);
    }

    for (int jt = 0; jt < 8; ++jt) {
        const int j0 = jbase + jt * 128;
        int labj[4]; float sqj[4];
        #pragma unroll
        for (int nt = 0; nt < 4; ++nt) {
            int j = j0 + wn * 64 + nt * 16 + c16;
            labj[nt] = labels[j];
            sqj[nt]  = sq[j];
        }

        f32x4 acc[2][4];
        #pragma unroll
        for (int mt = 0; mt < 2; ++mt)
            #pragma unroll
            for (int nt = 0; nt < 4; ++nt)
                acc[mt][nt] = (f32x4){0.f, 0.f, 0.f, 0.f};

        for (int kc = 0; kc < 4; ++kc) {
            __syncthreads();   // prev kc readers done (also covers A stage)
            #pragma unroll
            for (int h = 0; h < 4; ++h) {
                int cid = h * 256 + tid;      // 0..1023
                int r = cid >> 3, c = cid & 7;
                *(float4*)(Bs + r * 64 + (c ^ (r & 7)) * 8) =
                    *(const float4*)(fnb + (size_t)(j0 + r) * ND + kc * 64 + c * 8);
            }
            __syncthreads();
            #pragma unroll
            for (int ks = 0; ks < 2; ++ks) {
                bf16x8 af[2], bfr[4];
                #pragma unroll
                for (int mt = 0; mt < 2; ++mt) {
                    int r = wm * 32 + mt * 16 + c16;
                    int c = kc * 8 + ks * 4 + q;
                    af[mt] = *(const bf16x8*)(As + r * 256 + (c ^ (r & 7)) * 8);
                }
                #pragma unroll
                for (int nt = 0; nt < 4; ++nt) {
                    int r = wn * 64 + nt * 16 + c16;
                    int c = ks * 4 + q;
                    bfr[nt] = *(const bf16x8*)(Bs + r * 64 + (c ^ (r & 7)) * 8);
                }
                #pragma unroll
                for (int mt = 0; mt < 2; ++mt)
                    #pragma unroll
                    for (int nt = 0; nt < 4; ++nt)
                        acc[mt][nt] = __builtin_amdgcn_mfma_f32_16x16x32_bf16(
                            af[mt], bfr[nt], acc[mt][nt], 0, 0, 0);
            }
        }

        // ---- per-tile epilogue: accumulate into register stats ----
        #pragma unroll
        for (int mt = 0; mt < 2; ++mt) {
            #pragma unroll
            for (int reg = 0; reg < 4; ++reg) {
                int k = mt * 4 + reg;
                #pragma unroll
                for (int nt = 0; nt < 4; ++nt) {
                    float dot = acc[mt][nt][reg];
                    float d2  = fmaf(-2.0f, dot, sqi[k] + sqj[nt]);
                    bool same = (labi[k] == labj[nt]);
                    if (PASS == 1) {
                        bool p = same && (d2 < POS2);
                        mnd2[k] = fminf(mnd2[k], p ? d2 : F_INF);
                        mxd2[k] = fmaxf(mxd2[k], same ? F_NINF : d2);
                    } else {
                        float dist = sqrtf(fmaxf(d2, 1e-12f));
                        bool tkp = same && (d2 < tpos[k]);
                        bool tkn = !same && (d2 > tneg[k]);
                        float arg = fmaf(same ? 2.0f : -40.0f, dist,
                                         same ? -1.4f : 40.0f);
                        float e = __expf(arg);
                        ps[k] += tkp ? e : 0.f;
                        ns[k] += tkn ? e : 0.f;
                        pc[k] += tkp ? 1.f : 0.f;
                    }
                }
            }
        }
    }

    // ---- once per WG: reduce across the 16 c16 lanes, then atomics ----
    #pragma unroll
    for (int k = 0; k < 8; ++k) {
        int i = i0 + wm * 32 + (k >> 2) * 16 + q * 4 + (k & 3);
        if (PASS == 1) {
            #pragma unroll
            for (int off = 8; off > 0; off >>= 1) {
                mnd2[k] = fminf(mnd2[k], __shfl_xor(mnd2[k], off, 64));
                mxd2[k] = fmaxf(mxd2[k], __shfl_xor(mxd2[k], off, 64));
            }
            if (c16 == 0) {
                // at most one sub-zero candidate per row (the diagonal),
                // so int ordering == float ordering for the winner
                atomicMin((int*)&minpos_d2[i], __float_as_int(mnd2[k]));
                atomicMax((int*)&maxneg_d2[i], __float_as_int(mxd2[k]));
            }
        } else {
            #pragma unroll
            for (int off = 8; off > 0; off >>= 1) {
                ns[k] += __shfl_xor(ns[k], off, 64);
                ps[k] += __shfl_xor(ps[k], off, 64);
                pc[k] += __shfl_xor(pc[k], off, 64);
            }
            if (c16 == 0) {
                atomicAdd(&negsum[i], ns[k]);
                atomicAdd(&possum[i], ps[k]);
                atomicAdd(&poscnt[i], pc[k]);
            }
        }
    }
}

// ------------------------------------------------------------- finalize
__global__ void finalize_kernel(const float* __restrict__ negsum,
                                const float* __restrict__ possum,
                                const float* __restrict__ poscnt,
                                float* out) {
    int i = blockIdx.x * 256 + threadIdx.x;
    float v = 0.f;
    if (i < NB) {
        // each neg term >= e^-40 > 0, so negsum>0 <=> neg count >= 1
        bool valid = (negsum[i] > 0.f) && (poscnt[i] >= 0.5f);
        if (valid) {
            float nl = log1pf(negsum[i]) * (1.0f / 40.0f);
            float pl = log1pf(possum[i]) / (poscnt[i] + 1e-5f);
            v = nl + pl;
        }
    }
    #pragma unroll
    for (int off = 32; off > 0; off >>= 1) v += __shfl_xor(v, off, 64);
    __shared__ float red[4];
    if ((threadIdx.x & 63) == 0) red[threadIdx.x >> 6] = v;
    __syncthreads();
    if (threadIdx.x == 0)
        atomicAdd(out, (red[0] + red[1] + red[2] + red[3]) * (1.0f / NB));
}

// ------------------------------------------------------------ launcher
extern "C" void kernel_launch(void* const* d_in, const int* in_sizes, int n_in,
                              void* d_out, int out_size, void* d_ws, size_t ws_size,
                              hipStream_t stream) {
    const float* feats  = (const float*)d_in[0];
    const int*   labels = (const int*)d_in[1];
    float* out = (float*)d_out;

    // workspace: fnb bf16[NB*ND] (4 MB) then fp32 row arrays
    unsigned short* fnb = (unsigned short*)d_ws;
    float* sqv       = (float*)(fnb + (size_t)NB * ND);
    float* minpos_d2 = sqv + NB;
    float* maxneg_d2 = minpos_d2 + NB;
    float* negsum    = maxneg_d2 + NB;
    float* possum    = negsum + NB;
    float* poscnt    = possum + NB;

    init_kernel<<<NB / 256, 256, 0, stream>>>(minpos_d2, maxneg_d2, negsum,
                                              possum, poscnt, out);
    normalize_kernel<<<NB / 4, 256, 0, stream>>>(feats, fnb, sqv);

    dim3 grid(NB / 64, NB / 1024);   // 128 x 8 = 1024 workgroups
    pass_kernel<1><<<grid, 256, 0, stream>>>(fnb, sqv, labels, minpos_d2,
                                             maxneg_d2, negsum, possum, poscnt);
    pass_kernel<2><<<grid, 256, 0, stream>>>(fnb, sqv, labels, minpos_d2,
                                             maxneg_d2, negsum, possum, poscnt);
    finalize_kernel<<<NB / 256, 256, 0, stream>>>(negsum, possum, poscnt, out);
}

// Round 4
// 209.740 us; speedup vs baseline: 5.2899x; 1.1228x over previous
//
#include <hip/hip_runtime.h>
#include <math.h>

// Problem constants (B=8192 rows, D=256 features)
#define NB 8192
#define ND 256

using bf16x8 = __attribute__((ext_vector_type(8))) short;  // 8 bf16 in 4 VGPRs
using f32x4  = __attribute__((ext_vector_type(4))) float;  // MFMA C/D frag

#define POS2 0.99998000f   // (1 - 1e-5)^2, pos_mask_ threshold in d2 space
#define F_INF  __int_as_float(0x7f800000)
#define F_NINF __int_as_float(0xff800000)

__device__ __forceinline__ unsigned short f2bf(float x) {  // RNE fp32->bf16
    unsigned u = __float_as_uint(x);
    return (unsigned short)((u + 0x7fffu + ((u >> 16) & 1u)) >> 16);
}
__device__ __forceinline__ float bf2f(unsigned short b) {
    return __uint_as_float(((unsigned)b) << 16);
}

// async global->LDS, 16 B per lane; LDS dest = wave-uniform base + lane*16
__device__ __forceinline__ void gload_lds16(const unsigned short* g,
                                            unsigned short* l) {
    __builtin_amdgcn_global_load_lds(
        (const __attribute__((address_space(1))) void*)g,
        (__attribute__((address_space(3))) void*)l, 16, 0, 0);
}

// ---------------------------------------------------------------- init
__global__ void init_kernel(float* minpos_d2, float* maxneg_d2, float* negsum,
                            float* possum, float* poscnt, float* out) {
    int i = blockIdx.x * 256 + threadIdx.x;
    if (i < NB) {
        minpos_d2[i] = F_INF;
        maxneg_d2[i] = F_NINF;
        negsum[i] = 0.f; possum[i] = 0.f; poscnt[i] = 0.f;
    }
    if (blockIdx.x == 0 && threadIdx.x == 0) out[0] = 0.f;
}

// ---------------------------------------------------------- normalize
__global__ void normalize_kernel(const float* __restrict__ feats,
                                 unsigned short* __restrict__ fnb,
                                 float* __restrict__ sq) {
    int row = blockIdx.x * 4 + (threadIdx.x >> 6);
    int lane = threadIdx.x & 63;
    float4 v = ((const float4*)(feats + (size_t)row * ND))[lane];
    float s = v.x*v.x + v.y*v.y + v.z*v.z + v.w*v.w;
    #pragma unroll
    for (int off = 32; off > 0; off >>= 1) s += __shfl_xor(s, off, 64);
    float inv = 1.0f / (sqrtf(s) + 1e-12f);
    ushort4 w;
    w.x = f2bf(v.x * inv); w.y = f2bf(v.y * inv);
    w.z = f2bf(v.z * inv); w.w = f2bf(v.w * inv);
    ((ushort4*)(fnb + (size_t)row * ND))[lane] = w;
    float ax = bf2f(w.x), ay = bf2f(w.y), az = bf2f(w.z), aw = bf2f(w.w);
    float s2 = ax*ax + ay*ay + az*az + aw*aw;
    #pragma unroll
    for (int off = 32; off > 0; off >>= 1) s2 += __shfl_xor(s2, off, 64);
    if (lane == 0) sq[row] = s2;
}

// ---------------------------------------------------- fused MFMA passes
// WG tile: 64 i-rows x 1024 j-cols (8 j-tiles of 128). A (64x256 bf16,
// 32 KB) staged ONCE via global_load_lds; B chunk (128x64, 16 KB) staged
// per kc via global_load_lds (XOR swizzle applied on the global address
// side: LDS slot sc holds global chunk sc^(r&7)). Stats accumulate in
// registers across the whole j-chunk; one reduce+atomic set per WG.
// grid = (8 j-chunks, 128 i-tiles): linear id % 8 == j-chunk -> all WGs
// sharing a B slab land on one XCD (L2 locality).
template <int PASS>
__global__ __launch_bounds__(256, 3) void pass_kernel(
    const unsigned short* __restrict__ fnb, const float* __restrict__ sq,
    const int* __restrict__ labels,
    float* __restrict__ minpos_d2, float* __restrict__ maxneg_d2,
    float* __restrict__ negsum, float* __restrict__ possum,
    float* __restrict__ poscnt)
{
    __shared__ __align__(16) unsigned short As[64 * 256];  // 32 KB, full K
    __shared__ __align__(16) unsigned short Bs[128 * 64];  // 16 KB, one kc

    const int tid  = threadIdx.x;
    const int lane = tid & 63;
    const int wid  = tid >> 6;
    const int wm   = wid >> 1;       // wave row (0..1) -> 32 i-rows
    const int wn   = wid & 1;        // wave col (0..1) -> 64 j-cols
    const int q    = lane >> 4;
    const int c16  = lane & 15;
    const int i0    = blockIdx.y * 64;
    const int jbase = blockIdx.x * 1024;

    // ---- stage A once, async: wave w covers rows [w*16, w*16+16) ----
    // inst t: 2 rows (1 KB). lane l: row r0+(l>>5), slot sc=l&31 holds
    // global chunk (sc&24)|((sc^r)&7).
    {
        const int r0w = wid * 16;
        #pragma unroll
        for (int t = 0; t < 8; ++t) {
            int r0 = r0w + t * 2;
            int r  = r0 + (lane >> 5);
            int sc = lane & 31;
            int c  = (sc & 24) | ((sc ^ r) & 7);
            gload_lds16(fnb + (size_t)(i0 + r) * ND + c * 8, As + r0 * 256);
        }
    }

    // ---- per-lane i-row invariants (8 rows: (k>>2)*16 + q*4 + (k&3)) ----
    int   labi[8]; float sqi[8];
    float mnd2[8], mxd2[8];          // pass 1 accumulators
    float tneg[8], tpos[8];          // pass 2 thresholds (d2 space)
    float ns[8], ps[8], pc[8];       // pass 2 accumulators
    #pragma unroll
    for (int k = 0; k < 8; ++k) {
        int i = i0 + wm * 32 + (k >> 2) * 16 + q * 4 + (k & 3);
        labi[k] = labels[i];
        sqi[k]  = sq[i];
        if (PASS == 1) {
            mnd2[k] = F_INF; mxd2[k] = F_NINF;
        } else {
            float mp = sqrtf(fmaxf(minpos_d2[i], 1e-12f));
            float tn = mp - 0.1f;
            tneg[k] = (tn <= 0.f) ? -3.0f : tn * tn;        // d2 > tneg
            float mx = sqrtf(fmaxf(maxneg_d2[i], 1e-12f));
            float tp = mx + 0.1f;
            tpos[k] = fminf(tp * tp, POS2);                 // d2 < tpos
            ns[k] = 0.f; ps[k] = 0.f; pc[k] = 0.f;
        }
    }

    for (int jt = 0; jt < 8; ++jt) {
        const int j0 = jbase + jt * 128;
        int labj[4]; float sqj[4];
        #pragma unroll
        for (int nt = 0; nt < 4; ++nt) {
            int j = j0 + wn * 64 + nt * 16 + c16;
            labj[nt] = labels[j];
            sqj[nt]  = sq[j];
        }

        f32x4 acc[2][4];
        #pragma unroll
        for (int mt = 0; mt < 2; ++mt)
            #pragma unroll
            for (int nt = 0; nt < 4; ++nt)
                acc[mt][nt] = (f32x4){0.f, 0.f, 0.f, 0.f};

        for (int kc = 0; kc < 4; ++kc) {
            __syncthreads();   // prev readers of Bs done
            // stage B async: wave w rows [w*32, w*32+32), inst t: 8 rows.
            {
                int r0 = wid * 32 + 0;
                #pragma unroll
                for (int t = 0; t < 4; ++t) {
                    int rb = wid * 32 + t * 8;
                    int r  = rb + (lane >> 3);
                    int sc = lane & 7;
                    int c  = sc ^ (r & 7);
                    gload_lds16(fnb + (size_t)(j0 + r) * ND + kc * 64 + c * 8,
                                Bs + rb * 64);
                }
                (void)r0;
            }
            __syncthreads();   // vmcnt(0) drain + barrier: Bs (and As) ready
            #pragma unroll
            for (int ks = 0; ks < 2; ++ks) {
                bf16x8 af[2], bfr[4];
                #pragma unroll
                for (int mt = 0; mt < 2; ++mt) {
                    int r = wm * 32 + mt * 16 + c16;
                    int c = kc * 8 + ks * 4 + q;
                    int sc = (c & 24) | ((c ^ r) & 7);
                    af[mt] = *(const bf16x8*)(As + r * 256 + sc * 8);
                }
                #pragma unroll
                for (int nt = 0; nt < 4; ++nt) {
                    int r = wn * 64 + nt * 16 + c16;
                    int c = ks * 4 + q;
                    bfr[nt] = *(const bf16x8*)(Bs + r * 64 + (c ^ (r & 7)) * 8);
                }
                #pragma unroll
                for (int mt = 0; mt < 2; ++mt)
                    #pragma unroll
                    for (int nt = 0; nt < 4; ++nt)
                        acc[mt][nt] = __builtin_amdgcn_mfma_f32_16x16x32_bf16(
                            af[mt], bfr[nt], acc[mt][nt], 0, 0, 0);
            }
        }

        // ---- per-tile epilogue: accumulate into register stats ----
        #pragma unroll
        for (int mt = 0; mt < 2; ++mt) {
            #pragma unroll
            for (int reg = 0; reg < 4; ++reg) {
                int k = mt * 4 + reg;
                #pragma unroll
                for (int nt = 0; nt < 4; ++nt) {
                    float dot = acc[mt][nt][reg];
                    float d2  = fmaf(-2.0f, dot, sqi[k] + sqj[nt]);
                    bool same = (labi[k] == labj[nt]);
                    if (PASS == 1) {
                        bool p = same && (d2 < POS2);
                        mnd2[k] = fminf(mnd2[k], p ? d2 : F_INF);
                        mxd2[k] = fmaxf(mxd2[k], same ? F_NINF : d2);
                    } else {
                        float dist = sqrtf(fmaxf(d2, 1e-12f));
                        bool tkp = same && (d2 < tpos[k]);
                        bool tkn = !same && (d2 > tneg[k]);
                        float arg = fmaf(same ? 2.0f : -40.0f, dist,
                                         same ? -1.4f : 40.0f);
                        float e = __expf(arg);
                        ps[k] += tkp ? e : 0.f;
                        ns[k] += tkn ? e : 0.f;
                        pc[k] += tkp ? 1.f : 0.f;
                    }
                }
            }
        }
    }

    // ---- once per WG: reduce across the 16 c16 lanes, then atomics ----
    #pragma unroll
    for (int k = 0; k < 8; ++k) {
        int i = i0 + wm * 32 + (k >> 2) * 16 + q * 4 + (k & 3);
        if (PASS == 1) {
            #pragma unroll
            for (int off = 8; off > 0; off >>= 1) {
                mnd2[k] = fminf(mnd2[k], __shfl_xor(mnd2[k], off, 64));
                mxd2[k] = fmaxf(mxd2[k], __shfl_xor(mxd2[k], off, 64));
            }
            if (c16 == 0) {
                // at most one sub-zero candidate per row (the diagonal),
                // so int ordering == float ordering for the winner
                atomicMin((int*)&minpos_d2[i], __float_as_int(mnd2[k]));
                atomicMax((int*)&maxneg_d2[i], __float_as_int(mxd2[k]));
            }
        } else {
            #pragma unroll
            for (int off = 8; off > 0; off >>= 1) {
                ns[k] += __shfl_xor(ns[k], off, 64);
                ps[k] += __shfl_xor(ps[k], off, 64);
                pc[k] += __shfl_xor(pc[k], off, 64);
            }
            if (c16 == 0) {
                atomicAdd(&negsum[i], ns[k]);
                atomicAdd(&possum[i], ps[k]);
                atomicAdd(&poscnt[i], pc[k]);
            }
        }
    }
}

// ------------------------------------------------------------- finalize
__global__ void finalize_kernel(const float* __restrict__ negsum,
                                const float* __restrict__ possum,
                                const float* __restrict__ poscnt,
                                float* out) {
    int i = blockIdx.x * 256 + threadIdx.x;
    float v = 0.f;
    if (i < NB) {
        // each neg term >= e^-40 > 0, so negsum>0 <=> neg count >= 1
        bool valid = (negsum[i] > 0.f) && (poscnt[i] >= 0.5f);
        if (valid) {
            float nl = log1pf(negsum[i]) * (1.0f / 40.0f);
            float pl = log1pf(possum[i]) / (poscnt[i] + 1e-5f);
            v = nl + pl;
        }
    }
    #pragma unroll
    for (int off = 32; off > 0; off >>= 1) v += __shfl_xor(v, off, 64);
    __shared__ float red[4];
    if ((threadIdx.x & 63) == 0) red[threadIdx.x >> 6] = v;
    __syncthreads();
    if (threadIdx.x == 0)
        atomicAdd(out, (red[0] + red[1] + red[2] + red[3]) * (1.0f / NB));
}

// ------------------------------------------------------------ launcher
extern "C" void kernel_launch(void* const* d_in, const int* in_sizes, int n_in,
                              void* d_out, int out_size, void* d_ws, size_t ws_size,
                              hipStream_t stream) {
    const float* feats  = (const float*)d_in[0];
    const int*   labels = (const int*)d_in[1];
    float* out = (float*)d_out;

    // workspace: fnb bf16[NB*ND] (4 MB) then fp32 row arrays
    unsigned short* fnb = (unsigned short*)d_ws;
    float* sqv       = (float*)(fnb + (size_t)NB * ND);
    float* minpos_d2 = sqv + NB;
    float* maxneg_d2 = minpos_d2 + NB;
    float* negsum    = maxneg_d2 + NB;
    float* possum    = negsum + NB;
    float* poscnt    = possum + NB;

    init_kernel<<<NB / 256, 256, 0, stream>>>(minpos_d2, maxneg_d2, negsum,
                                              possum, poscnt, out);
    normalize_kernel<<<NB / 4, 256, 0, stream>>>(feats, fnb, sqv);

    dim3 grid(NB / 1024, NB / 64);   // (8 j-chunks, 128 i-tiles)
    pass_kernel<1><<<grid, 256, 0, stream>>>(fnb, sqv, labels, minpos_d2,
                                             maxneg_d2, negsum, possum, poscnt);
    pass_kernel<2><<<grid, 256, 0, stream>>>(fnb, sqv, labels, minpos_d2,
                                             maxneg_d2, negsum, possum, poscnt);
    finalize_kernel<<<NB / 256, 256, 0, stream>>>(negsum, possum, poscnt, out);
}